// Round 12
// baseline (128.157 us; speedup 1.0000x reference)
//
#include <hip/hip_runtime.h>
#include <hip/hip_bf16.h>

#define DIM   1024
#define HEADS 16
#define B     2
#define N     2048
#define BLKS_PER_BH 64   // 64 blocks sweep one bh plane together
#define ITERS (N / BLKS_PER_BH)   // 32 rows per block

typedef float f32x4 __attribute__((ext_vector_type(4)));

__device__ __forceinline__ float logsig(float z) {
  return fminf(z, 0.0f) - log1pf(__expf(-fabsf(z)));
}

// ---------------------------------------------------------------------------
// Kernel 1: logits[b,h,n] = dot(x[b,n,:], W[h,:]) + bias[h]
// One block per (b,n). 256 threads = 4 waves; each wave computes 4 heads.
// ---------------------------------------------------------------------------
__global__ __launch_bounds__(256) void logits_kernel(
    const float* __restrict__ x, const float* __restrict__ W,
    const float* __restrict__ bias, float* __restrict__ logits) {
  const int bn   = blockIdx.x;
  const int tid  = threadIdx.x;
  const int wave = tid >> 6;
  const int lane = tid & 63;

  const f32x4* xrow = (const f32x4*)(x + (size_t)bn * DIM);
  f32x4 xv[4];
#pragma unroll
  for (int k = 0; k < 4; ++k) xv[k] = xrow[lane * 4 + k];

#pragma unroll
  for (int hh = 0; hh < 4; ++hh) {
    const int h = wave * 4 + hh;
    const f32x4* wrow = (const f32x4*)(W + (size_t)h * DIM);
    float s = 0.0f;
#pragma unroll
    for (int k = 0; k < 4; ++k) {
      f32x4 wv = wrow[lane * 4 + k];
      s += wv.x * xv[k].x + wv.y * xv[k].y + wv.z * xv[k].z + wv.w * xv[k].w;
    }
#pragma unroll
    for (int off = 32; off > 0; off >>= 1) s += __shfl_down(s, off, 64);
    if (lane == 0) {
      const int b = bn >> 11;
      const int n = bn & (N - 1);
      logits[((size_t)(b * HEADS + h)) * N + n] = s + bias[h];
    }
  }
}

// ---------------------------------------------------------------------------
// Kernel 2 (fused cumsum + outer, SWEEPING write front): 2048 blocks (8/CU),
// 64 blocks per bh. Block kk of a bh writes rows i = kk + it*64 — at any
// instant the 64 sibling blocks write one contiguous 512 KB window that
// sweeps the 16 MB bh-plane (globally dense write front, fill-style).
// Steady state per row: 1 LDS broadcast + 2 coalesced 16B stores, no loads.
// ---------------------------------------------------------------------------
__global__ __launch_bounds__(256) void fused_outer_kernel(
    const float* __restrict__ logits, float* __restrict__ out) {
  const int blk  = blockIdx.x;        // 0..2047
  const int bh   = blk >> 6;          // 64 blocks per bh
  const int kk   = blk & (BLKS_PER_BH - 1);
  const int tid  = threadIdx.x;
  const int lane = tid & 63;
  const int wave = tid >> 6;

  __shared__ float fgrow[N];          // 8 KB cumsum row for this bh
  __shared__ float wtot[4];

  // ---- prologue: fg row = cumsum(logsig(logits[bh,:])) (identical math)
  {
    const float* lp = logits + (size_t)bh * N;
    f32x4 a = ((const f32x4*)lp)[tid * 2];
    f32x4 c = ((const f32x4*)lp)[tid * 2 + 1];
    float v[8] = {a.x, a.y, a.z, a.w, c.x, c.y, c.z, c.w};

    float run = 0.0f;
#pragma unroll
    for (int i = 0; i < 8; ++i) { v[i] = logsig(v[i]); run += v[i]; v[i] = run; }
    const float total = run;

    float sc = total;
#pragma unroll
    for (int off = 1; off < 64; off <<= 1) {
      float t = __shfl_up(sc, off, 64);
      if (lane >= off) sc += t;
    }
    if (lane == 63) wtot[wave] = sc;
    __syncthreads();
    float wofs = 0.0f;
    for (int w = 0; w < wave; ++w) wofs += wtot[w];

    const float base = wofs + sc - total;
    f32x4 o0 = {base + v[0], base + v[1], base + v[2], base + v[3]};
    f32x4 o1 = {base + v[4], base + v[5], base + v[6], base + v[7]};
    ((f32x4*)fgrow)[tid * 2]     = o0;
    ((f32x4*)fgrow)[tid * 2 + 1] = o1;
  }
  __syncthreads();

  // ---- sweep: 32 rows at stride 64; siblings form a dense moving window
  const f32x4 v0 = ((const f32x4*)fgrow)[tid];
  const f32x4 v1 = ((const f32x4*)fgrow)[tid + 256];

  f32x4* oplane = (f32x4*)(out + (size_t)bh * N * N);
#pragma unroll 4
  for (int it = 0; it < ITERS; ++it) {
    const int i = kk + it * BLKS_PER_BH;
    const float f = fgrow[i];         // LDS broadcast
    f32x4 r0 = {f - v0.x, f - v0.y, f - v0.z, f - v0.w};
    f32x4 r1 = {f - v1.x, f - v1.y, f - v1.z, f - v1.w};
    f32x4* orow = oplane + (size_t)i * (N / 4);
    orow[tid]       = r0;
    orow[tid + 256] = r1;
  }
}

extern "C" void kernel_launch(void* const* d_in, const int* in_sizes, int n_in,
                              void* d_out, int out_size, void* d_ws, size_t ws_size,
                              hipStream_t stream) {
  const float* x    = (const float*)d_in[0];   // [B, N, DIM]
  const float* W    = (const float*)d_in[1];   // [HEADS, DIM]
  const float* bias = (const float*)d_in[2];   // [HEADS]
  float* out = (float*)d_out;                  // [B, HEADS, N, N]

  float* logits = (float*)d_ws;                // 256 KB scratch

  logits_kernel<<<B * N, 256, 0, stream>>>(x, W, bias, logits);
  fused_outer_kernel<<<B * HEADS * BLKS_PER_BH, 256, 0, stream>>>(logits, out);
}

// Round 13
// 112.894 us; speedup vs baseline: 1.1352x; 1.1352x over previous
//
#include <hip/hip_runtime.h>
#include <hip/hip_bf16.h>

#define DIM   1024
#define HEADS 16
#define B     2
#define N     2048
#define ROWS_K1 8         // bn rows per block in logits kernel
#define ROWS_PER_BLK 32   // fused outer: 32 output rows per block (r10, best)

typedef float f32x4 __attribute__((ext_vector_type(4)));

__device__ __forceinline__ float logsig(float z) {
  return fminf(z, 0.0f) - log1pf(__expf(-fabsf(z)));
}

// ---------------------------------------------------------------------------
// Kernel 1 v2: logits[b,h,n] = dot(x[b,n,:], W[h,:]) + bias[h]
// 512 blocks x 8 bn-rows. Each wave owns 4 heads; its W fragments live in
// 64 VGPRs, loaded ONCE per block (8x less W cache traffic than v1).
// ---------------------------------------------------------------------------
__global__ __launch_bounds__(256) void logits_kernel(
    const float* __restrict__ x, const float* __restrict__ W,
    const float* __restrict__ bias, float* __restrict__ logits) {
  const int bn0  = blockIdx.x * ROWS_K1;
  const int tid  = threadIdx.x;
  const int wave = tid >> 6;
  const int lane = tid & 63;

  // preload W for this wave's 4 heads: wv[h][k] -> 64 VGPRs
  f32x4 wv[4][4];
#pragma unroll
  for (int hh = 0; hh < 4; ++hh) {
    const f32x4* wrow = (const f32x4*)(W + (size_t)(wave * 4 + hh) * DIM);
#pragma unroll
    for (int k = 0; k < 4; ++k) wv[hh][k] = wrow[lane * 4 + k];
  }
  // bias for the 4 heads (scalar, uniform)
  float bsc[4];
#pragma unroll
  for (int hh = 0; hh < 4; ++hh) bsc[hh] = bias[wave * 4 + hh];

  for (int r = 0; r < ROWS_K1; ++r) {
    const int bn = bn0 + r;
    const f32x4* xrow = (const f32x4*)(x + (size_t)bn * DIM);
    f32x4 xv[4];
#pragma unroll
    for (int k = 0; k < 4; ++k) xv[k] = xrow[lane * 4 + k];

#pragma unroll
    for (int hh = 0; hh < 4; ++hh) {
      float s = 0.0f;
#pragma unroll
      for (int k = 0; k < 4; ++k) {
        f32x4 w4 = wv[hh][k];
        s += w4.x * xv[k].x + w4.y * xv[k].y + w4.z * xv[k].z + w4.w * xv[k].w;
      }
#pragma unroll
      for (int off = 32; off > 0; off >>= 1) s += __shfl_down(s, off, 64);
      if (lane == 0) {
        const int b = bn >> 11;
        const int n = bn & (N - 1);
        logits[((size_t)(b * HEADS + wave * 4 + hh)) * N + n] = s + bsc[hh];
      }
    }
  }
}

// ---------------------------------------------------------------------------
// Kernel 2 (fused cumsum + outer): r10 structure verbatim (best: 119.2 us).
// Each block recomputes its bh's fg row into LDS, then writes 32 consecutive
// output rows; all 4 waves jointly write one 8 KB row. 2048 blocks, 8/CU.
// ---------------------------------------------------------------------------
__global__ __launch_bounds__(256) void fused_outer_kernel(
    const float* __restrict__ logits, float* __restrict__ out) {
  const int blk  = blockIdx.x;        // 0..2047
  const int bh   = blk >> 6;          // 64 blocks per bh
  const int i0   = (blk & 63) * ROWS_PER_BLK;
  const int tid  = threadIdx.x;
  const int lane = tid & 63;
  const int wave = tid >> 6;

  __shared__ float fgrow[N];          // 8 KB cumsum row for this bh
  __shared__ float wtot[4];

  // ---- prologue: fg row = cumsum(logsig(logits[bh,:]))
  {
    const float* lp = logits + (size_t)bh * N;
    f32x4 a = ((const f32x4*)lp)[tid * 2];
    f32x4 c = ((const f32x4*)lp)[tid * 2 + 1];
    float v[8] = {a.x, a.y, a.z, a.w, c.x, c.y, c.z, c.w};

    float run = 0.0f;
#pragma unroll
    for (int i = 0; i < 8; ++i) { v[i] = logsig(v[i]); run += v[i]; v[i] = run; }
    const float total = run;

    float sc = total;
#pragma unroll
    for (int off = 1; off < 64; off <<= 1) {
      float t = __shfl_up(sc, off, 64);
      if (lane >= off) sc += t;
    }
    if (lane == 63) wtot[wave] = sc;
    __syncthreads();
    float wofs = 0.0f;
    for (int w = 0; w < wave; ++w) wofs += wtot[w];

    const float base = wofs + sc - total;
    f32x4 o0 = {base + v[0], base + v[1], base + v[2], base + v[3]};
    f32x4 o1 = {base + v[4], base + v[5], base + v[6], base + v[7]};
    ((f32x4*)fgrow)[tid * 2]     = o0;
    ((f32x4*)fgrow)[tid * 2 + 1] = o1;
  }
  __syncthreads();

  // ---- epilogue: 32 consecutive rows, block writes each row jointly
  const f32x4 v0 = ((const f32x4*)fgrow)[tid];
  const f32x4 v1 = ((const f32x4*)fgrow)[tid + 256];

  f32x4* orow = (f32x4*)(out + ((size_t)(bh * N + i0)) * N);
#pragma unroll 4
  for (int r = 0; r < ROWS_PER_BLK; ++r) {
    const float f = fgrow[i0 + r];    // LDS broadcast
    f32x4 r0 = {f - v0.x, f - v0.y, f - v0.z, f - v0.w};
    f32x4 r1 = {f - v1.x, f - v1.y, f - v1.z, f - v1.w};
    orow[tid]       = r0;
    orow[tid + 256] = r1;
    orow += N / 4;                    // next consecutive row
  }
}

extern "C" void kernel_launch(void* const* d_in, const int* in_sizes, int n_in,
                              void* d_out, int out_size, void* d_ws, size_t ws_size,
                              hipStream_t stream) {
  const float* x    = (const float*)d_in[0];   // [B, N, DIM]
  const float* W    = (const float*)d_in[1];   // [HEADS, DIM]
  const float* bias = (const float*)d_in[2];   // [HEADS]
  float* out = (float*)d_out;                  // [B, HEADS, N, N]

  float* logits = (float*)d_ws;                // 256 KB scratch

  logits_kernel<<<B * N / ROWS_K1, 256, 0, stream>>>(x, W, bias, logits);
  fused_outer_kernel<<<B * HEADS * (N / ROWS_PER_BLK), 256, 0, stream>>>(logits, out);
}